// Round 3
// baseline (657.121 us; speedup 1.0000x reference)
//
#include <hip/hip_runtime.h>

#define SROWS 16384
#define DIMK  4096
#define NE    64
#define BRK   64                 // rows per block (lane = row)
#define NBLK  (SROWS/BRK)        // 256 blocks = 1/CU
#define DC    64                 // D-chunk staged in LDS
#define PITCH 68                 // padded row pitch (canonical b128 bank pattern)
#define NCH   (DIMK/DC)          // 64 chunks
#define NW    8                  // waves per block
#define XBUF  (BRK*PITCH)        // 4352 floats per buffer

__global__ __launch_bounds__(512, 2) void gate_main(
    const float* __restrict__ x, const float* __restrict__ W,
    const float* __restrict__ b, float* __restrict__ out, float* __restrict__ ws)
{
    __shared__ float xl[2 * XBUF];      // 34816 B, double-buffered x tile
    __shared__ float Lb[NE * 65];       // 16640 B, logits for epilogue
    __shared__ float red[2 * NW * 64];  // 4096 B, imp/cnt partials

    const int tid  = threadIdx.x;
    const int lane = tid & 63;
    const int wid  = __builtin_amdgcn_readfirstlane(tid >> 6);  // 0..7
    const int blk  = blockIdx.x;
    const int row0 = blk * BRK;

    // staging role: 1024 float4 per chunk / 512 threads = 2 each
    const int sr0 = tid >> 4;            // 0..31
    const int sc  = (tid & 15) * 4;      // float col within chunk
    const float* xg0 = x + (size_t)(row0 + sr0) * DIMK + sc;
    const float* xg1 = xg0 + (size_t)32 * DIMK;
    const int sd0 = sr0 * PITCH + sc;
    const int sd1 = sd0 + 32 * PITCH;

    // prologue: stage chunk 0 into buffer 0
    *reinterpret_cast<float4*>(&xl[sd0]) = *reinterpret_cast<const float4*>(xg0);
    *reinterpret_cast<float4*>(&xl[sd1]) = *reinterpret_cast<const float4*>(xg1);
    __syncthreads();

    float4 acc[8];
    #pragma unroll
    for (int j = 0; j < 8; ++j) acc[j] = make_float4(0.f, 0.f, 0.f, 0.f);

    // this wave's 8 experts (wave-uniform -> W goes through the scalar path)
    const float* wb = W + (size_t)(wid * 8) * DIMK;

    #pragma unroll 1
    for (int ch = 0; ch < NCH; ++ch) {
        const float* cb = &xl[(ch & 1) * XBUF];
        const bool hn = (ch + 1) < NCH;
        float4 p0, p1;
        if (hn) {
            p0 = *reinterpret_cast<const float4*>(xg0 + (size_t)(ch + 1) * DC);
            p1 = *reinterpret_cast<const float4*>(xg1 + (size_t)(ch + 1) * DC);
        }

        // hoist this lane's whole x chunk into registers: one LDS burst
        float4 xq[16];
        #pragma unroll
        for (int q = 0; q < 16; ++q)
            xq[q] = *reinterpret_cast<const float4*>(&cb[lane * PITCH + q * 4]);

        const float* wc = wb + (size_t)ch * DC;
        #pragma unroll
        for (int qp = 0; qp < 8; ++qp) {
            // batch 16 scalar W loads (8 experts x quad-pair), then 64 fmacs
            float4 wA[8], wB[8];
            #pragma unroll
            for (int j = 0; j < 8; ++j) {
                wA[j] = *reinterpret_cast<const float4*>(&wc[(size_t)j * DIMK + qp * 8]);
                wB[j] = *reinterpret_cast<const float4*>(&wc[(size_t)j * DIMK + qp * 8 + 4]);
            }
            const float4 xa = xq[2 * qp];
            const float4 xb = xq[2 * qp + 1];
            #pragma unroll
            for (int j = 0; j < 8; ++j) {
                acc[j].x = fmaf(xa.x, wA[j].x, acc[j].x);
                acc[j].y = fmaf(xa.y, wA[j].y, acc[j].y);
                acc[j].z = fmaf(xa.z, wA[j].z, acc[j].z);
                acc[j].w = fmaf(xa.w, wA[j].w, acc[j].w);
                acc[j].x = fmaf(xb.x, wB[j].x, acc[j].x);
                acc[j].y = fmaf(xb.y, wB[j].y, acc[j].y);
                acc[j].z = fmaf(xb.z, wB[j].z, acc[j].z);
                acc[j].w = fmaf(xb.w, wB[j].w, acc[j].w);
            }
        }

        if (hn) {
            float* nb = &xl[((ch + 1) & 1) * XBUF];
            *reinterpret_cast<float4*>(&nb[sd0]) = p0;
            *reinterpret_cast<float4*>(&nb[sd1]) = p1;
        }
        __syncthreads();
    }

    // ---- logits to LDS: Lb[e*65 + row] ----
    #pragma unroll
    for (int j = 0; j < 8; ++j)
        Lb[(wid * 8 + j) * 65 + lane] =
            (acc[j].x + acc[j].y) + (acc[j].z + acc[j].w);
    __syncthreads();

    // ---- epilogue: softmax + top-2 per row (lane = expert), 8 rows/wave ----
    float impAcc = 0.f, cntAcc = 0.f;
    const float blane = b[lane];
    float* outIdx = out;
    float* outVal = out + (size_t)SROWS * 2;

    #pragma unroll 1
    for (int rr = 0; rr < 8; ++rr) {
        const int r = wid * 8 + rr;
        const float logit = Lb[lane * 65 + r] + blane;

        // argmax with lowest-index tie-break (matches jax.lax.top_k)
        float v1 = logit; int i1 = lane;
        #pragma unroll
        for (int off = 32; off; off >>= 1) {
            float ov = __shfl_xor(v1, off);
            int   oi = __shfl_xor(i1, off);
            if (ov > v1 || (ov == v1 && oi < i1)) { v1 = ov; i1 = oi; }
        }
        float p = expf(logit - v1);
        float ssum = p;
        #pragma unroll
        for (int off = 32; off; off >>= 1) ssum += __shfl_xor(ssum, off);

        float v2 = (lane == i1) ? -3.402823466e38f : logit;
        int i2 = lane;
        #pragma unroll
        for (int off = 32; off; off >>= 1) {
            float ov = __shfl_xor(v2, off);
            int   oi = __shfl_xor(i2, off);
            if (ov > v2 || (ov == v2 && oi < i2)) { v2 = ov; i2 = oi; }
        }

        impAcc += p / ssum;
        cntAcc += (i1 == lane) ? 1.f : 0.f;

        if (lane == 0) {
            const int sr = row0 + r;
            outIdx[sr * 2 + 0] = (float)i1;
            outIdx[sr * 2 + 1] = (float)i2;
            outVal[sr * 2 + 0] = 1.f / ssum;
            outVal[sr * 2 + 1] = expf(v2 - v1) / ssum;
        }
    }

    // ---- per-block reduce of importance / count partials ----
    __syncthreads();
    red[wid * 64 + lane]            = impAcc;
    red[NW * 64 + wid * 64 + lane]  = cntAcc;
    __syncthreads();
    if (tid < 64) {
        float si = 0.f, sc2 = 0.f;
        #pragma unroll
        for (int g = 0; g < NW; ++g) {
            si  += red[g * 64 + tid];
            sc2 += red[NW * 64 + g * 64 + tid];
        }
        ws[(size_t)blk * 64 + tid] = si;
        ws[(size_t)NBLK * 64 + (size_t)blk * 64 + tid] = sc2;
    }
}

__global__ void gate_reduce(const float* __restrict__ ws, float* __restrict__ out)
{
    __shared__ float li[4 * 64], lc[4 * 64], lp[64];
    const int t = threadIdx.x;
    const int e = t & 63, g = t >> 6;
    float si = 0.f, sc = 0.f;
    const int per = NBLK / 4;     // 64
    for (int bb = g * per; bb < (g + 1) * per; ++bb) {
        si += ws[(size_t)bb * 64 + e];
        sc += ws[(size_t)NBLK * 64 + (size_t)bb * 64 + e];
    }
    li[g * 64 + e] = si;
    lc[g * 64 + e] = sc;
    __syncthreads();
    if (t < 64) {
        float ti = 0.f, tc = 0.f;
        #pragma unroll
        for (int gg = 0; gg < 4; ++gg) { ti += li[gg * 64 + t]; tc += lc[gg * 64 + t]; }
        lp[t] = ti * tc;
    }
    __syncthreads();
    if (t == 0) {
        float s = 0.f;
        for (int i = 0; i < NE; ++i) s += lp[i];
        out[(size_t)SROWS * 4] = s * ((float)NE / ((float)SROWS * (float)SROWS));
    }
}

extern "C" void kernel_launch(void* const* d_in, const int* in_sizes, int n_in,
                              void* d_out, int out_size, void* d_ws, size_t ws_size,
                              hipStream_t stream)
{
    const float* x = (const float*)d_in[0];
    const float* W = (const float*)d_in[1];
    const float* b = (const float*)d_in[2];
    float* out = (float*)d_out;
    float* ws  = (float*)d_ws;

    gate_main<<<NBLK, 512, 0, stream>>>(x, W, b, out, ws);
    gate_reduce<<<1, 256, 0, stream>>>(ws, out);
}

// Round 4
// 111.042 us; speedup vs baseline: 5.9178x; 5.9178x over previous
//
#include <hip/hip_runtime.h>

#define SROWS 16384
#define DIMK  4096
#define NE    64
#define BM    64
#define NBLK  (SROWS/BM)     // 256 blocks
#define BK    32             // k per chunk (one K32 MFMA step)
#define KSEG  2048           // k-range per k-split half
#define NCHK  (KSEG/BK)      // 64 chunks
#define APB   80             // LDS row pitch bytes (40 bf16, 16B-aligned rows)
#define AKS   5120           // per-ks array stride (64 rows * 80 B)
#define NW    8

typedef __attribute__((ext_vector_type(8))) short short8;
typedef __attribute__((ext_vector_type(4))) float f32x4;

__device__ __forceinline__ unsigned short bf16_rne(float f) {
    unsigned u = __float_as_uint(f);
    return (unsigned short)((u + 0x7fffu + ((u >> 16) & 1u)) >> 16);
}

// split float4 -> 4 hi bf16 (packed uint2) + 4 lo bf16 (packed uint2)
__device__ __forceinline__ void split4(float4 v, uint2& hp, uint2& lp) {
    unsigned short h[4], l[4];
    float f[4] = {v.x, v.y, v.z, v.w};
    #pragma unroll
    for (int i = 0; i < 4; ++i) {
        h[i] = bf16_rne(f[i]);
        float hif = __uint_as_float((unsigned)h[i] << 16);
        l[i] = bf16_rne(f[i] - hif);
    }
    hp.x = (unsigned)h[0] | ((unsigned)h[1] << 16);
    hp.y = (unsigned)h[2] | ((unsigned)h[3] << 16);
    lp.x = (unsigned)l[0] | ((unsigned)l[1] << 16);
    lp.y = (unsigned)l[2] | ((unsigned)l[3] << 16);
}

__global__ __launch_bounds__(512, 2) void gate_main(
    const float* __restrict__ x, const float* __restrict__ W,
    const float* __restrict__ b, float* __restrict__ out, float* __restrict__ ws)
{
    __shared__ __align__(16) char smemc[40960];
    char* const Ah = smemc;            // [2 ks][64 rows][40 bf16]
    char* const Al = smemc + 10240;
    char* const Wh = smemc + 20480;    // [2 ks][64 experts][40 bf16]
    char* const Wl = smemc + 30720;

    const int tid  = threadIdx.x;
    const int lane = tid & 63;
    const int wid  = __builtin_amdgcn_readfirstlane(tid >> 6);  // 0..7
    const int blk  = blockIdx.x;
    const int row0 = blk * BM;

    // staging role: thread handles (row/expert sr, f4-slot ss) for both ks halves
    const int sr = tid >> 3;       // 0..63
    const int ss = tid & 7;        // 0..7 (f4 slot in 32-float chunk)
    const float* xg = x + (size_t)(row0 + sr) * DIMK + ss * 4;
    const float* wg = W + (size_t)sr * DIMK + ss * 4;

    // prefetch chunk 0 (both k-split halves)
    float4 pa[2], pw[2];
    #pragma unroll
    for (int i = 0; i < 2; ++i) {
        pa[i] = *reinterpret_cast<const float4*>(xg + i * KSEG);
        pw[i] = *reinterpret_cast<const float4*>(wg + i * KSEG);
    }

    f32x4 acc[4];
    #pragma unroll
    for (int n = 0; n < 4; ++n) acc[n] = (f32x4){0.f, 0.f, 0.f, 0.f};

    const int ksw = wid >> 2;      // this wave's k-split half
    const int mw  = wid & 3;       // this wave's 16-row M-tile
    const int aoff = ksw * AKS + (mw * 16 + (lane & 15)) * APB + (lane >> 4) * 16;
    const int boff = ksw * AKS + (lane & 15) * APB + (lane >> 4) * 16;

    #pragma unroll 1
    for (int ch = 0; ch < NCHK; ++ch) {
        // convert current prefetch regs -> LDS (hi/lo bf16)
        #pragma unroll
        for (int i = 0; i < 2; ++i) {
            uint2 hA, lA, hW, lW;
            split4(pa[i], hA, lA);
            split4(pw[i], hW, lW);
            const int so = i * AKS + sr * APB + ss * 8;
            *reinterpret_cast<uint2*>(Ah + so) = hA;
            *reinterpret_cast<uint2*>(Al + so) = lA;
            *reinterpret_cast<uint2*>(Wh + so) = hW;
            *reinterpret_cast<uint2*>(Wl + so) = lW;
        }
        __syncthreads();

        // issue next chunk's global loads (latency hides under compute)
        if (ch + 1 < NCHK) {
            #pragma unroll
            for (int i = 0; i < 2; ++i) {
                pa[i] = *reinterpret_cast<const float4*>(xg + i * KSEG + (ch + 1) * BK);
                pw[i] = *reinterpret_cast<const float4*>(wg + i * KSEG + (ch + 1) * BK);
            }
        }

        // fragments from LDS
        short8 ah = *reinterpret_cast<const short8*>(Ah + aoff);
        short8 al = *reinterpret_cast<const short8*>(Al + aoff);
        short8 bh[4], bl[4];
        #pragma unroll
        for (int n = 0; n < 4; ++n) {
            bh[n] = *reinterpret_cast<const short8*>(Wh + boff + n * 16 * APB);
            bl[n] = *reinterpret_cast<const short8*>(Wl + boff + n * 16 * APB);
        }

        // bf16x4: hh + hl + lh + ll
        #pragma unroll
        for (int n = 0; n < 4; ++n)
            acc[n] = __builtin_amdgcn_mfma_f32_16x16x32_bf16(ah, bh[n], acc[n], 0, 0, 0);
        #pragma unroll
        for (int n = 0; n < 4; ++n)
            acc[n] = __builtin_amdgcn_mfma_f32_16x16x32_bf16(ah, bl[n], acc[n], 0, 0, 0);
        #pragma unroll
        for (int n = 0; n < 4; ++n)
            acc[n] = __builtin_amdgcn_mfma_f32_16x16x32_bf16(al, bh[n], acc[n], 0, 0, 0);
        #pragma unroll
        for (int n = 0; n < 4; ++n)
            acc[n] = __builtin_amdgcn_mfma_f32_16x16x32_bf16(al, bl[n], acc[n], 0, 0, 0);

        __syncthreads();
    }

    // ---- k-pair reduce (ks=1 waves dump, ks=0 waves sum) ----
    float* part = reinterpret_cast<float*>(smemc);           // 16 KB
    float* Lb   = reinterpret_cast<float*>(smemc + 16384);   // 64x65 f32
    float* red  = reinterpret_cast<float*>(smemc + 33024);   // 2*NW*64 f32

    if (wid >= 4) {
        #pragma unroll
        for (int n = 0; n < 4; ++n)
            #pragma unroll
            for (int j = 0; j < 4; ++j)
                part[(wid - 4) * 1024 + lane * 16 + n * 4 + j] = acc[n][j];
    }
    __syncthreads();
    if (wid < 4) {
        #pragma unroll
        for (int n = 0; n < 4; ++n) {
            #pragma unroll
            for (int j = 0; j < 4; ++j) {
                float v = acc[n][j] + part[wid * 1024 + lane * 16 + n * 4 + j];
                // C layout (m89-verified): col = lane&15, row = (lane>>4)*4 + j
                const int e  = n * 16 + (lane & 15);
                const int rl = mw * 16 + (lane >> 4) * 4 + j;
                Lb[e * 65 + rl] = v;
            }
        }
    }
    __syncthreads();

    // ---- epilogue (R2-proven): softmax + top-2 per row, lane = expert ----
    float impAcc = 0.f, cntAcc = 0.f;
    const float blane = b[lane];
    float* outIdx = out;
    float* outVal = out + (size_t)SROWS * 2;

    #pragma unroll 1
    for (int rr = 0; rr < 8; ++rr) {
        const int r = wid * 8 + rr;
        const float logit = Lb[lane * 65 + r] + blane;

        float v1 = logit; int i1 = lane;
        #pragma unroll
        for (int off = 32; off; off >>= 1) {
            float ov = __shfl_xor(v1, off);
            int   oi = __shfl_xor(i1, off);
            if (ov > v1 || (ov == v1 && oi < i1)) { v1 = ov; i1 = oi; }
        }
        float p = expf(logit - v1);
        float ssum = p;
        #pragma unroll
        for (int off = 32; off; off >>= 1) ssum += __shfl_xor(ssum, off);

        float v2 = (lane == i1) ? -3.402823466e38f : logit;
        int i2 = lane;
        #pragma unroll
        for (int off = 32; off; off >>= 1) {
            float ov = __shfl_xor(v2, off);
            int   oi = __shfl_xor(i2, off);
            if (ov > v2 || (ov == v2 && oi < i2)) { v2 = ov; i2 = oi; }
        }

        impAcc += p / ssum;
        cntAcc += (i1 == lane) ? 1.f : 0.f;

        if (lane == 0) {
            const int sr2 = row0 + r;
            outIdx[sr2 * 2 + 0] = (float)i1;
            outIdx[sr2 * 2 + 1] = (float)i2;
            outVal[sr2 * 2 + 0] = 1.f / ssum;
            outVal[sr2 * 2 + 1] = expf(v2 - v1) / ssum;
        }
    }

    // ---- per-block reduce of importance / count partials ----
    __syncthreads();
    red[wid * 64 + lane]           = impAcc;
    red[NW * 64 + wid * 64 + lane] = cntAcc;
    __syncthreads();
    if (tid < 64) {
        float si = 0.f, sc2 = 0.f;
        #pragma unroll
        for (int g = 0; g < NW; ++g) {
            si  += red[g * 64 + tid];
            sc2 += red[NW * 64 + g * 64 + tid];
        }
        ws[(size_t)blk * 64 + tid] = si;
        ws[(size_t)NBLK * 64 + (size_t)blk * 64 + tid] = sc2;
    }
}

__global__ void gate_reduce(const float* __restrict__ ws, float* __restrict__ out)
{
    __shared__ float li[4 * 64], lc[4 * 64], lp[64];
    const int t = threadIdx.x;
    const int e = t & 63, g = t >> 6;
    float si = 0.f, sc = 0.f;
    const int per = NBLK / 4;     // 64
    for (int bb = g * per; bb < (g + 1) * per; ++bb) {
        si += ws[(size_t)bb * 64 + e];
        sc += ws[(size_t)NBLK * 64 + (size_t)bb * 64 + e];
    }
    li[g * 64 + e] = si;
    lc[g * 64 + e] = sc;
    __syncthreads();
    if (t < 64) {
        float ti = 0.f, tc = 0.f;
        #pragma unroll
        for (int gg = 0; gg < 4; ++gg) { ti += li[gg * 64 + t]; tc += lc[gg * 64 + t]; }
        lp[t] = ti * tc;
    }
    __syncthreads();
    if (t == 0) {
        float s = 0.f;
        for (int i = 0; i < NE; ++i) s += lp[i];
        out[(size_t)SROWS * 4] = s * ((float)NE / ((float)SROWS * (float)SROWS));
    }
}

extern "C" void kernel_launch(void* const* d_in, const int* in_sizes, int n_in,
                              void* d_out, int out_size, void* d_ws, size_t ws_size,
                              hipStream_t stream)
{
    const float* x = (const float*)d_in[0];
    const float* W = (const float*)d_in[1];
    const float* b = (const float*)d_in[2];
    float* out = (float*)d_out;
    float* ws  = (float*)d_ws;

    gate_main<<<NBLK, 512, 0, stream>>>(x, W, b, out, ws);
    gate_reduce<<<1, 256, 0, stream>>>(ws, out);
}